// Round 3
// baseline (200.646 us; speedup 1.0000x reference)
//
#include <hip/hip_runtime.h>

// Problem constants: N=50000, E=100000, F=80000, B=64, S=32, T=32, D=3
#define NB     64
#define SS     32
#define TT     32
#define RADIUS 1.1f
#define SHARP  500.0f
#define TC     4                    // thetas per block
#define NTCH   8                    // t-chunks (TT/TC)
#define BAND   0.05f                // exact-sigmoid band half-width (500*0.05=25)
#define CELLS  (SS * NB * TC)       // 8192 cells per t-chunk tile
#define MAXCHUNK 128

// ---------------- Phase 1: node heights nh4[tchunk][n][4] ----------------
__global__ __launch_bounds__(256) void wect_nh(
    const float* __restrict__ x, const float* __restrict__ v,
    float* __restrict__ nh4, int Nn)
{
    const int idx = blockIdx.x * 256 + threadIdx.x;
    const int n = idx >> 5;
    const int t = idx & 31;
    if (n >= Nn) return;
    const float x0 = x[3 * n], x1 = x[3 * n + 1], x2 = x[3 * n + 2];
    const float h = x0 * v[t] + x1 * v[TT + t] + x2 * v[2 * TT + t];
    nh4[(((size_t)(t >> 2)) * Nn + n) * 4 + (t & 3)] = h;
}

// ---------------- Phase 1b: per-simplex meta (indices, batch, signed weight) ----
__global__ __launch_bounds__(256) void wect_meta(
    const float* __restrict__ nw, const int* __restrict__ ei,
    const int* __restrict__ fc, const int* __restrict__ batch,
    int4* __restrict__ idx4, float* __restrict__ swgt,
    int Nn, int E, int F)
{
    const int m = blockIdx.x * 256 + threadIdx.x;
    const int M = Nn + E + F;
    if (m >= M) return;
    int i0, i1, i2; float w, sgn;
    if (m < Nn) {
        i0 = i1 = i2 = m; w = nw[m]; sgn = 1.0f;
    } else if (m < Nn + E) {
        const int e = m - Nn;
        i0 = ei[e]; i1 = ei[E + e]; i2 = i0;
        w = fmaxf(nw[i0], nw[i1]); sgn = -1.0f;
    } else {
        const int f = m - Nn - E;
        i0 = fc[f]; i1 = fc[F + f]; i2 = fc[2 * F + f];
        w = fmaxf(nw[i0], fmaxf(nw[i1], nw[i2])); sgn = 1.0f;
    }
    idx4[m] = make_int4(i0, i1, i2, batch[i0]);
    swgt[m] = sgn * w;
}

// ---------------- Main: delta-domain accumulate into LDS, store partials ----
__global__ __launch_bounds__(256) void wect_main(
    const float4* __restrict__ nh4,   // [NTCH][Nn] float4
    const int4*   __restrict__ idx4,  // [M]
    const float*  __restrict__ swgt,  // [M]
    const float*  __restrict__ lin,   // [S]
    float*        __restrict__ partial, // [nchunk*NTCH][CELLS]
    int Nn, int M, int nchunk)
{
    __shared__ float acc[CELLS];      // layout [b][tc][s]  (bank = s)

    const int tid    = threadIdx.x;
    const int tchunk = blockIdx.x & 7;        // t-chunk == XCD slot (round-robin)
    const int chunk  = blockIdx.x >> 3;

    for (int i = tid; i < CELLS; i += 256) acc[i] = 0.0f;
    __syncthreads();

    const float4* nh4t = nh4 + (size_t)tchunk * Nn;
    const float step     = (2.0f * RADIUS) / (float)(SS - 1);
    const float inv_step = 1.0f / step;

    for (int m = chunk * 256 + tid; m < M; m += 256 * nchunk) {
        const int4  q   = idx4[m];        // coalesced 16B
        const float wsg = swgt[m];        // coalesced
        const float4 a0 = nh4t[q.x];      // one dwordx4 gather per vertex
        const float4 a1 = nh4t[q.y];
        const float4 a2 = nh4t[q.z];
        const float hh[4] = {
            fminf(a0.x, fminf(a1.x, a2.x)),
            fminf(a0.y, fminf(a1.y, a2.y)),
            fminf(a0.z, fminf(a1.z, a2.z)),
            fminf(a0.w, fminf(a1.w, a2.w)) };
        float* accb = &acc[q.w * (TC * SS)];

#pragma unroll
        for (int tc = 0; tc < TC; ++tc) {
            const float h = hh[tc];
            const float ulo = (h - BAND + RADIUS) * inv_step;
            const float uhi = (h + BAND + RADIUS) * inv_step;
            int sA = (int)ceilf(ulo);  if (sA < 0) sA = 0;
            const int sBr = (int)floorf(uhi);
            int sB = sBr; if (sB > SS - 1) sB = SS - 1;
            float* a = accb + tc * SS;
            for (int s = sA; s <= sB; ++s) {
                const float z   = SHARP * (lin[s] - h);
                const float sig = 1.0f / (1.0f + __expf(-z));
                const float val = wsg * sig;
                atomicAdd(&a[s], val);
                if (s + 1 < SS) atomicAdd(&a[s + 1], -val);
            }
            int sfx = sBr + 1; if (sfx < 0) sfx = 0;
            if (sfx < SS) atomicAdd(&a[sfx], wsg);
        }
    }
    __syncthreads();

    float* dst = partial + (size_t)blockIdx.x * CELLS;   // [chunk][tchunk][cells]
    for (int i = tid; i < CELLS; i += 256) dst[i] = acc[i];
}

// ---------------- Reduce: sum partials over chunks (coalesced) ----------------
__global__ __launch_bounds__(256) void wect_reduce1(
    const float* __restrict__ partial, float* __restrict__ ws3, int nchunk)
{
    const int idx    = blockIdx.x * 256 + threadIdx.x;   // 0 .. NTCH*CELLS-1
    const int tchunk = idx >> 13;
    const int cell   = idx & (CELLS - 1);
    float s = 0.0f;
    for (int c = 0; c < nchunk; ++c)
        s += partial[((size_t)(c * NTCH + tchunk)) * CELLS + cell];
    ws3[idx] = s;
}

// ---------------- Prefix over s + scatter to out[b][s][t] ----------------
__global__ __launch_bounds__(256) void wect_reduce2p(
    const float* __restrict__ ws3, float* __restrict__ out)
{
    const int idx = blockIdx.x * 256 + threadIdx.x;      // 0..2047
    const int tchunk = idx >> 8;                         // / (NB*TC)
    const int btc    = idx & 255;                        // b*4+tc
    const int b  = btc >> 2;
    const int tc = btc & 3;
    const float* src = ws3 + ((size_t)tchunk << 13) + btc * SS;
    float run = 0.0f;
#pragma unroll
    for (int s = 0; s < SS; ++s) {
        run += src[s];
        out[(b * SS + s) * TT + tchunk * TC + tc] = run;
    }
}

extern "C" void kernel_launch(void* const* d_in, const int* in_sizes, int n_in,
                              void* d_out, int out_size, void* d_ws, size_t ws_size,
                              hipStream_t stream)
{
    const float* x     = (const float*)d_in[0];
    const float* nw    = (const float*)d_in[1];
    const float* v     = (const float*)d_in[2];
    const float* lin   = (const float*)d_in[3];
    const int*   ei    = (const int*)d_in[4];
    const int*   fc    = (const int*)d_in[5];
    const int*   batch = (const int*)d_in[6];
    float*       out   = (float*)d_out;

    const int Nn = in_sizes[1];
    const int E  = in_sizes[4] / 2;
    const int F  = in_sizes[5] / 3;
    const int M  = Nn + E + F;

    // ws layout: nh4 | idx4 | swgt | ws3 | partial   (256B-aligned chunks)
    auto align256 = [](size_t b) { return (b + 255) & ~(size_t)255; };
    const size_t nh4_b  = align256((size_t)Nn * NTCH * TC * sizeof(float));
    const size_t idx4_b = align256((size_t)M * sizeof(int4));
    const size_t swgt_b = align256((size_t)M * sizeof(float));
    const size_t ws3_b  = align256((size_t)NTCH * CELLS * sizeof(float));
    const size_t unit_b = (size_t)NTCH * CELLS * sizeof(float);   // 256 KB per chunk
    const size_t base   = nh4_b + idx4_b + swgt_b + ws3_b;

    int nchunk = 1;
    if (ws_size > base) nchunk = (int)((ws_size - base) / unit_b);
    if (nchunk > MAXCHUNK) nchunk = MAXCHUNK;
    if (nchunk < 1) nchunk = 1;

    float* nh4     = (float*)d_ws;
    int4*  idx4    = (int4*)((char*)d_ws + nh4_b);
    float* swgt    = (float*)((char*)d_ws + nh4_b + idx4_b);
    float* ws3     = (float*)((char*)d_ws + nh4_b + idx4_b + swgt_b);
    float* partial = (float*)((char*)d_ws + base);

    wect_nh<<<(Nn * 32 + 255) / 256, 256, 0, stream>>>(x, v, nh4, Nn);
    wect_meta<<<(M + 255) / 256, 256, 0, stream>>>(nw, ei, fc, batch, idx4, swgt, Nn, E, F);
    wect_main<<<NTCH * nchunk, 256, 0, stream>>>(
        (const float4*)nh4, idx4, swgt, lin, partial, Nn, M, nchunk);
    wect_reduce1<<<NTCH * CELLS / 256, 256, 0, stream>>>(partial, ws3, nchunk);
    wect_reduce2p<<<NTCH * NB * TC / 256, 256, 0, stream>>>(ws3, out);
}

// Round 4
// 108.237 us; speedup vs baseline: 1.8538x; 1.8538x over previous
//
#include <hip/hip_runtime.h>

// Problem constants: N=50000, E=100000, F=80000, B=64, S=32, T=32, D=3
#define NB     64
#define SS     32
#define TT     32
#define RADIUS 1.1f
#define SHARP  500.0f
#define NC     32          // chunks per graph -> grid = 64*32 = 2048 blocks
#define CAP    2048        // LDS compaction list capacity (== max matches per round)

// ---------- node heights nh[n*32 + t] ----------
__global__ __launch_bounds__(256) void k_nh(
    const float* __restrict__ x, const float* __restrict__ v,
    float* __restrict__ nh, int Nn)
{
    const int idx = blockIdx.x * 256 + threadIdx.x;
    if (idx >= Nn * TT) return;
    const int n = idx >> 5, t = idx & 31;
    nh[idx] = x[3 * n] * v[t] + x[3 * n + 1] * v[TT + t] + x[3 * n + 2] * v[2 * TT + t];
}

// ---------- edge/face meta: efi = {i0,i1,i2, bits(w_signed)}, efb = graph id ----------
__global__ __launch_bounds__(256) void k_meta(
    const float* __restrict__ nw, const int* __restrict__ ei,
    const int* __restrict__ fc, const int* __restrict__ batch,
    int4* __restrict__ efi, int* __restrict__ efb, int E, int F)
{
    const int j = blockIdx.x * 256 + threadIdx.x;
    if (j >= E + F) return;
    int i0, i1, i2; float w;
    if (j < E) {                       // edge: subtract, min over 2 (set i2=i0)
        i0 = ei[j]; i1 = ei[E + j]; i2 = i0;
        w = -fmaxf(nw[i0], nw[i1]);
    } else {                           // face: add, min over 3
        const int f = j - E;
        i0 = fc[f]; i1 = fc[F + f]; i2 = fc[2 * F + f];
        w = fmaxf(nw[i0], fmaxf(nw[i1], nw[i2]));
    }
    efi[j] = make_int4(i0, i1, i2, __float_as_int(w));
    efb[j] = batch[i0];
}

// ---------- node ranges: ns[b] = lower_bound(batch, b), b in [0,64] ----------
__global__ void k_ranges(const int* __restrict__ batch, int* __restrict__ ns, int Nn)
{
    const int b = threadIdx.x;
    if (b > NB) return;
    int lo = 0, hi = Nn;
    while (lo < hi) { const int mid = (lo + hi) >> 1; if (batch[mid] < b) lo = mid + 1; else hi = mid; }
    ns[b] = lo;
}

// ---------- main: output-stationary dense accumulation, no atomics in hot path ----------
__global__ __launch_bounds__(256) void k_main(
    const float* __restrict__ nh, const float* __restrict__ nw,
    const float* __restrict__ lin, const int4* __restrict__ efi,
    const int* __restrict__ efb, const int* __restrict__ ns,
    float* __restrict__ partial, int EF)
{
    __shared__ int list[CAP];
    __shared__ int cnt;

    const int b     = blockIdx.x >> 5;        // / NC
    const int chunk = blockIdx.x & (NC - 1);
    const int tid   = threadIdx.x;
    const int t     = tid & 31;               // theta
    const int sq    = tid >> 5;               // s-quad: cells s = sq*4 .. sq*4+3

    // per-cell thresholds scaled by sharpness
    const float c0 = SHARP * lin[sq * 4 + 0];
    const float c1 = SHARP * lin[sq * 4 + 1];
    const float c2 = SHARP * lin[sq * 4 + 2];
    const float c3 = SHARP * lin[sq * 4 + 3];
    float a0 = 0.f, a1 = 0.f, a2 = 0.f, a3 = 0.f;

    // ---- nodes of graph b (contiguous range, sliced by chunk) ----
    const int nb0 = ns[b], nb1 = ns[b + 1];
    const int cn  = nb1 - nb0;
    const int u0  = nb0 + (cn * chunk) / NC;
    const int u1  = nb0 + (cn * (chunk + 1)) / NC;
    for (int n = u0; n < u1; ++n) {
        const float h = nh[n * 32 + t];       // one 128B line, broadcast across sq
        const float w = nw[n];                // uniform broadcast
        const float g = SHARP * h;
        a0 += w * __builtin_amdgcn_rcpf(1.f + __expf(g - c0));
        a1 += w * __builtin_amdgcn_rcpf(1.f + __expf(g - c1));
        a2 += w * __builtin_amdgcn_rcpf(1.f + __expf(g - c2));
        a3 += w * __builtin_amdgcn_rcpf(1.f + __expf(g - c3));
    }

    // ---- edges+faces: scan slice of efb, compact matches to LDS, process densely ----
    const int e0 = (EF * chunk) / NC;
    const int e1 = (EF * (chunk + 1)) / NC;
    for (int base = e0; base < e1; base += CAP) {
        if (tid == 0) cnt = 0;
        __syncthreads();
        const int take = min(e1 - base, CAP);
        for (int j = base + tid; j < base + take; j += 256)
            if (efb[j] == b) list[atomicAdd(&cnt, 1)] = j;
        __syncthreads();
        const int nm = cnt;
        for (int k = 0; k < nm; ++k) {
            const int4  q = efi[list[k]];     // broadcast
            const float w = __int_as_float(q.w);
            const float h = fminf(nh[q.x * 32 + t],
                            fminf(nh[q.y * 32 + t], nh[q.z * 32 + t]));
            const float g = SHARP * h;
            a0 += w * __builtin_amdgcn_rcpf(1.f + __expf(g - c0));
            a1 += w * __builtin_amdgcn_rcpf(1.f + __expf(g - c1));
            a2 += w * __builtin_amdgcn_rcpf(1.f + __expf(g - c2));
            a3 += w * __builtin_amdgcn_rcpf(1.f + __expf(g - c3));
        }
        __syncthreads();
    }

    // ---- flush per-(b,chunk) partial [1024] ----
    float* dst = partial + ((size_t)blockIdx.x << 10);
    dst[(sq * 4 + 0) * 32 + t] = a0;
    dst[(sq * 4 + 1) * 32 + t] = a1;
    dst[(sq * 4 + 2) * 32 + t] = a2;
    dst[(sq * 4 + 3) * 32 + t] = a3;
}

// ---------- reduce over chunks -> out[b][s][t] ----------
__global__ __launch_bounds__(256) void k_reduce(
    const float* __restrict__ partial, float* __restrict__ out)
{
    const int idx  = blockIdx.x * 256 + threadIdx.x;   // 0 .. 64*1024-1
    const int b    = idx >> 10;
    const int cell = idx & 1023;
    float s = 0.f;
    for (int c = 0; c < NC; ++c)
        s += partial[(((size_t)(b * NC + c)) << 10) + cell];
    out[idx] = s;
}

extern "C" void kernel_launch(void* const* d_in, const int* in_sizes, int n_in,
                              void* d_out, int out_size, void* d_ws, size_t ws_size,
                              hipStream_t stream)
{
    const float* x     = (const float*)d_in[0];
    const float* nw    = (const float*)d_in[1];
    const float* v     = (const float*)d_in[2];
    const float* lin   = (const float*)d_in[3];
    const int*   ei    = (const int*)d_in[4];
    const int*   fc    = (const int*)d_in[5];
    const int*   batch = (const int*)d_in[6];
    float*       out   = (float*)d_out;

    const int Nn = in_sizes[1];
    const int E  = in_sizes[4] / 2;
    const int F  = in_sizes[5] / 3;
    const int EF = E + F;

    auto align256 = [](size_t v_) { return (v_ + 255) & ~(size_t)255; };
    const size_t nh_b  = align256((size_t)Nn * TT * sizeof(float));      // 6.4 MB
    const size_t efi_b = align256((size_t)EF * sizeof(int4));            // 2.9 MB
    const size_t efb_b = align256((size_t)EF * sizeof(int));             // 0.72 MB
    const size_t ns_b  = align256((size_t)(NB + 1) * sizeof(int));
    // partial: NB*NC*1024 floats = 8 MB

    float* nh      = (float*)d_ws;
    int4*  efi     = (int4*)((char*)d_ws + nh_b);
    int*   efb     = (int*)((char*)d_ws + nh_b + efi_b);
    int*   ns      = (int*)((char*)d_ws + nh_b + efi_b + efb_b);
    float* partial = (float*)((char*)d_ws + nh_b + efi_b + efb_b + ns_b);

    k_nh    <<<(Nn * TT + 255) / 256, 256, 0, stream>>>(x, v, nh, Nn);
    k_meta  <<<(EF + 255) / 256,      256, 0, stream>>>(nw, ei, fc, batch, efi, efb, E, F);
    k_ranges<<<1, 128, 0, stream>>>(batch, ns, Nn);
    k_main  <<<NB * NC, 256, 0, stream>>>(nh, nw, lin, efi, efb, ns, partial, EF);
    k_reduce<<<NB * TT * SS / 256, 256, 0, stream>>>(partial, out);
}